// Round 6
// baseline (199.165 us; speedup 1.0000x reference)
//
#include <hip/hip_runtime.h>

#pragma clang fp contract(off)

namespace {
constexpr int NB = 2, ND = 100, MH = 28, MW = 28;
constexpr int OH = 512, OW = 512;
constexpr int SH = 128, SW = 128, NC = 32;
constexpr int BMP_ROWS = 172;
constexpr int BMP8_ROWWORDS = 8;                        // canvas-aligned words per row
constexpr int BMP8_DETWORDS = BMP_ROWS * BMP8_ROWWORDS; // 1376
constexpr int NSEG = (NB*OH*OW)/256;                    // 2048 seg blocks

// workspace layout (int32 word indices)
constexpr int OFF_COUNTS = 0;                     // NB*32
constexpr int OFF_AREA   = 64;                    // NB*ND
constexpr int OFF_ACC    = OFF_AREA + NB*ND;
constexpr int OFF_YB     = OFF_ACC  + NB*ND;
constexpr int OFF_VAL    = OFF_YB   + NB*ND;
constexpr int OFF_QN     = OFF_VAL  + NB*ND;
constexpr int OFF_SEGCLS = OFF_QN   + NB*ND;      // byte region: NB*OH*OW bytes
constexpr int OFF_BMP8   = OFF_SEGCLS + (NB*OH*OW)/4;
constexpr int OCC_STRIDE = 25;                    // odd stride -> conflict-free; q0+7 <= 22 < 25
constexpr int OCC_WORDS  = OH * OCC_STRIDE;       // 12800 words = 51.2 KB
static_assert(OFF_BMP8 % 4 == 0, "uint4 alignment");
}

// ================= K1: seg resize/argmax/counts + owner-init + per-det mask =================
__global__ void k_segmask(const float* __restrict__ boxes, const int* __restrict__ classes,
                          const float* __restrict__ scores, const float* __restrict__ dmasks,
                          const float* __restrict__ seg, int* __restrict__ wsI,
                          int* __restrict__ out) {
  const int bid = blockIdx.x, t = threadIdx.x;
  if (bid < NSEG) {
    // ---- seg part: bilinear 128->512, argmax, stuff counts; init owner plane ----
    const int pid = bid*256 + t;
    const int b = pid >> 18;
    const int p = pid & (OH*OW - 1);
    const int y = p >> 9, x = p & (OW - 1);
    __shared__ unsigned int hist[NC];
    if (t < NC) hist[t] = 0u;
    __syncthreads();

    out[pid] = 0x7FFFFFFF;                         // owner sentinel (plane 0)

    float syf = ((float)y + 0.5f) * 0.25f - 0.5f;
    float y0f = floorf(syf);
    float fy = syf - y0f;
    int y0 = (int)y0f, y1 = y0 + 1;
    if (y0 < 0)            { y0 = 0; y1 = 0; fy = 0.0f; }
    else if (y1 > SH - 1)  { y1 = SH - 1; fy = 0.0f; }
    float sxf = ((float)x + 0.5f) * 0.25f - 0.5f;
    float x0f = floorf(sxf);
    float fx = sxf - x0f;
    int x0 = (int)x0f, x1 = x0 + 1;
    if (x0 < 0)            { x0 = 0; x1 = 0; fx = 0.0f; }
    else if (x1 > SW - 1)  { x1 = SW - 1; fx = 0.0f; }
    float wy = 1.0f - fy, wx = 1.0f - fx;

    const float4* p00 = (const float4*)(seg + ((size_t)(b*SH + y0)*SW + x0)*NC);
    const float4* p01 = (const float4*)(seg + ((size_t)(b*SH + y0)*SW + x1)*NC);
    const float4* p10 = (const float4*)(seg + ((size_t)(b*SH + y1)*SW + x0)*NC);
    const float4* p11 = (const float4*)(seg + ((size_t)(b*SH + y1)*SW + x1)*NC);
    float best = -3.4e38f;
    int bi = 0;
    #pragma unroll
    for (int cc = 0; cc < NC/4; ++cc) {
      float4 a = p00[cc], bb = p01[cc], c2 = p10[cc], d = p11[cc];
      float av[4] = {a.x, a.y, a.z, a.w};
      float bv[4] = {bb.x, bb.y, bb.z, bb.w};
      float cv[4] = {c2.x, c2.y, c2.z, c2.w};
      float dv[4] = {d.x, d.y, d.z, d.w};
      #pragma unroll
      for (int j = 0; j < 4; ++j) {
        float t0 = wy*av[j] + fy*cv[j];   // height pass first (XLA dim order)
        float t1 = wy*bv[j] + fy*dv[j];
        float v  = wx*t0 + fx*t1;
        int ch = cc*4 + j;
        if (v > best) { best = v; bi = ch; }   // strict > = first max (jnp.argmax)
      }
    }
    ((unsigned char*)wsI)[OFF_SEGCLS*4 + pid] = (unsigned char)bi;
    if (bi >= 2) atomicAdd(&hist[bi], 1u);
    __syncthreads();
    if (t < NC) {
      unsigned int h = hist[t];
      if (h) atomicAdd((unsigned int*)&wsI[OFF_COUNTS + b*32 + t], h);
    }
    return;
  }
  // ---- mask part: one block per (b, sorted-rank k); local rank recompute ----
  const int g = bid - NSEG;            // b*ND + k
  const int b = g / ND, k = g - b*ND;
  __shared__ float s_sc[ND];
  __shared__ float sm[MH*MW];
  __shared__ int s_det, s_area;
  if (t < ND) s_sc[t] = scores[b*ND + t];
  if (t == 0) s_area = 0;
  __syncthreads();
  if (t < ND) {
    float sn = s_sc[t];
    int r = 0;
    for (int j = 0; j < ND; ++j) {
      float sj = s_sc[j];
      r += (sj > sn) || (sj == sn && j < t);   // stable descending rank
    }
    if (r == k) s_det = t;
  }
  __syncthreads();
  const int det = s_det;
  const int cls = classes[b*ND + det];          // uniform broadcast loads
  const float sc = s_sc[det];
  const float* bx = boxes + (size_t)(b*ND + det)*4;
  const float ymin = bx[0], xmin = bx[1], ymax = bx[2], xmax = bx[3];
  const bool keep = (sc > 0.5f) && (cls != 0);
  int ylo = (int)ceilf(ymin), yhi = (int)ceilf(ymax);
  int xlo = (int)ceilf(xmin), xhi = (int)ceilf(xmax);
  ylo = max(ylo, 0); xlo = max(xlo, 0);
  yhi = min(yhi, OH); xhi = min(xhi, OW);
  if (yhi < ylo) yhi = ylo;
  if (xhi < xlo) xhi = xlo;
  if (yhi - ylo > BMP_ROWS) yhi = ylo + BMP_ROWS;   // safety
  if (xhi - xlo > 192)      xhi = xlo + 192;        // safety
  if (!keep) { yhi = ylo; xhi = xlo; }
  const int rows = yhi - ylo, width = xhi - xlo;
  const int q0 = xlo >> 5;
  const int nw = (width > 0) ? (((xlo & 31) + width + 31) >> 5) : 0;
  if (t == 0) {
    wsI[OFF_YB  + g] = ylo | (yhi << 16);
    wsI[OFF_VAL + g] = (det + 1) | (cls << 16);
    wsI[OFF_QN  + g] = q0 | (nw << 16);
  }
  if (rows <= 0 || width <= 0) {
    if (t == 0) wsI[OFF_AREA + g] = 0;
    return;
  }
  const float hs  = (ymax > ymin) ? (28.0f / (ymax - ymin)) : 0.0f;
  const float wsc = (xmax > xmin) ? (28.0f / (xmax - xmin)) : 0.0f;
  const float* mp = dmasks + (size_t)(b*ND + det)*(MH*MW);
  for (int i = t; i < MH*MW; i += 256) sm[i] = mp[i];
  __syncthreads();
  unsigned int* bmp8 = (unsigned int*)wsI + OFF_BMP8 + g*BMP8_DETWORDS;
  const int iw = t >> 5, bit = t & 31;
  const int x = ((q0 + iw) << 5) + bit;
  const bool inbox = (x >= xlo) && (x < xhi);
  for (int r = 0; r < rows; ++r) {
    const int y = ylo + r;
    bool pred = false;
    if (inbox) {
      // exact op order of _paste_one (fp contract off)
      float ty = ((float)y + 0.5f); ty = ty - ymin; ty = ty * hs;  float my = ty - 0.5f;
      float tx = ((float)x + 0.5f); tx = tx - xmin; tx = tx * wsc; float mx = tx - 0.5f;
      float y0f = floorf(my), x0f = floorf(mx);
      float ly = my - y0f, lx = mx - x0f;
      int y0 = (int)y0f, x0 = (int)x0f;
      int y1 = min(max(y0 + 1, 0), MH - 1);
      int x1 = min(max(x0 + 1, 0), MW - 1);
      y0 = min(max(y0, 0), MH - 1);
      x0 = min(max(x0, 0), MW - 1);
      float v00 = sm[y0*MW + x0], v01 = sm[y0*MW + x1];
      float v10 = sm[y1*MW + x0], v11 = sm[y1*MW + x1];
      float omlx = 1.0f - lx, omly = 1.0f - ly;
      float top = omlx*v00 + lx*v01;
      float bot = omlx*v10 + lx*v11;
      float outv = omly*top + ly*bot;
      pred = outv > 0.5f;
    }
    unsigned long long m = __ballot(pred);
    unsigned int word = (t & 32) ? (unsigned int)(m >> 32) : (unsigned int)m;
    if (bit == 0) {
      bmp8[r*BMP8_ROWWORDS + iw] = word;
      if (word) atomicAdd(&s_area, __popc(word));
    }
  }
  __syncthreads();
  if (t == 0) wsI[OFF_AREA + g] = s_area;
}

// ================= K2: scan -> accept flags only =================
__device__ __forceinline__ void loadDet(const uint4* __restrict__ base, int g, int t, int yb,
                                        uint4 lo[3], uint4 hi[3]) {
  const int rows = (yb >> 16) - (yb & 0xffff);
  const uint4* p = base + (size_t)g*(BMP8_DETWORDS/4);
  #pragma unroll
  for (int j = 0; j < 3; ++j) {
    const int rr = t + j*64;
    if (rr < rows) { lo[j] = p[rr*2 + 0]; hi[j] = p[rr*2 + 1]; }
    else           { lo[j] = uint4{0,0,0,0}; hi[j] = uint4{0,0,0,0}; }
  }
}

__device__ __forceinline__ void processDet(int t, const uint4 lo[3], const uint4 hi[3],
                                           unsigned int* occ, int area, int yb, int q0,
                                           int* __restrict__ accp) {
  const int ylo = yb & 0xffff;
  const int rows = (yb >> 16) - ylo;
  unsigned int w[3][8], o[3][8];
  int rb_[3];
  int cnt = 0;
  #pragma unroll
  for (int j = 0; j < 3; ++j) {
    const int rr = t + j*64;
    const bool rv = rr < rows;
    const int rb = (ylo + (rv ? rr : 0)) * OCC_STRIDE + q0;
    rb_[j] = rb;
    w[j][0] = lo[j].x; w[j][1] = lo[j].y; w[j][2] = lo[j].z; w[j][3] = lo[j].w;
    w[j][4] = hi[j].x; w[j][5] = hi[j].y; w[j][6] = hi[j].z; w[j][7] = hi[j].w;
    #pragma unroll
    for (int i = 0; i < 8; ++i) {
      unsigned int ov = occ[rb + i];
      cnt += __popc(w[j][i] & ov);          // w already zero for invalid rows
      o[j][i] = ov;
    }
  }
  #pragma unroll
  for (int off = 32; off; off >>= 1) cnt += __shfl_xor(cnt, off);
  const bool acc = ((float)cnt / (float)area) < 0.5f;   // area>=1 (compacted list)
  if (acc) {
    if (t == 0) *accp = 1;
    #pragma unroll
    for (int j = 0; j < 3; ++j) {
      if (t + j*64 < rows) {
        #pragma unroll
        for (int i = 0; i < 8; ++i) occ[rb_[j] + i] = o[j][i] | w[j][i];
      }
    }
  }
}

__global__ void __launch_bounds__(64) k_scan(int* __restrict__ wsI) {
  const int b = blockIdx.x, t = threadIdx.x;   // 1 wave, lockstep
  __shared__ unsigned int occ[OCC_WORDS];      // 51.2 KB
  __shared__ int s_list[ND], s_area[ND], s_yb[ND], s_q0[ND];
  for (int i = t; i < OCC_WORDS; i += 64) occ[i] = 0u;
  for (int i = t; i < ND; i += 64) {
    s_area[i] = wsI[OFF_AREA + b*ND + i];
    s_yb[i]   = wsI[OFF_YB   + b*ND + i];
    s_q0[i]   = wsI[OFF_QN   + b*ND + i] & 0xffff;
    wsI[OFF_ACC + b*ND + i] = 0;
  }
  __syncthreads();
  int nact = 0;
  for (int base = 0; base < ND; base += 64) {
    int i = base + t;
    bool a = (i < ND) && (s_area[i] > 0);
    unsigned long long m = __ballot(a);
    int pos = nact + __popcll(m & ((1ull << t) - 1ull));
    if (a) s_list[pos] = i;
    nact += (int)__popcll(m);
  }
  __syncthreads();
  if (nact == 0) return;
  const uint4* bmp4 = (const uint4*)((unsigned int*)wsI + OFF_BMP8 + (size_t)b*ND*BMP8_DETWORDS);
  int* accB = wsI + OFF_ACC + b*ND;
  uint4 Alo[3], Ahi[3], Blo[3], Bhi[3], Clo[3], Chi[3];
  const int last = nact - 1;
  {
    int g0 = s_list[0], g1 = s_list[min(1, last)];
    loadDet(bmp4, g0, t, s_yb[g0], Alo, Ahi);
    loadDet(bmp4, g1, t, s_yb[g1], Blo, Bhi);
  }
  for (int ii = 0; ii < nact; ii += 3) {
    int gC = s_list[min(ii+2, last)];
    loadDet(bmp4, gC, t, s_yb[gC], Clo, Chi);
    { int g = s_list[ii];
      processDet(t, Alo, Ahi, occ, s_area[g], s_yb[g], s_q0[g], accB + g); }
    int gA = s_list[min(ii+3, last)];
    loadDet(bmp4, gA, t, s_yb[gA], Alo, Ahi);
    if (ii+1 < nact) { int g = s_list[ii+1];
      processDet(t, Blo, Bhi, occ, s_area[g], s_yb[g], s_q0[g], accB + g); }
    int gB = s_list[min(ii+4, last)];
    loadDet(bmp4, gB, t, s_yb[gB], Blo, Bhi);
    if (ii+2 < nact) { int g = s_list[ii+2];
      processDet(t, Clo, Chi, occ, s_area[g], s_yb[g], s_q0[g], accB + g); }
  }
}

// ================= K3: paint owners via atomicMin over original bitmaps =================
__global__ void k_paint(const int* __restrict__ wsI, int* __restrict__ out) {
  const int g = blockIdx.x;             // b*ND + k
  if (!wsI[OFF_ACC + g]) return;        // uniform
  const int t = threadIdx.x;            // 256 = 8 words x 32 bits
  const int b = g / ND, k = g - b*ND;
  const int yb = wsI[OFF_YB + g];
  const int ylo = yb & 0xffff;
  const int rows = (yb >> 16) - ylo;
  const int q0 = wsI[OFF_QN + g] & 0xffff;
  const unsigned int* bmp = (const unsigned int*)wsI + OFF_BMP8 + g*BMP8_DETWORDS;
  int* __restrict__ owner = out + b*(OH*OW);     // plane 0 doubles as owner map
  const int iw = t >> 5, bit = t & 31;
  const int x = ((q0 + iw) << 5) + bit;
  for (int r = 0; r < rows; ++r) {
    unsigned int wv = bmp[r*BMP8_ROWWORDS + iw];
    if ((wv >> bit) & 1u)
      atomicMin(&owner[(ylo + r)*OW + x], k);    // owner = min sorted rank (proven == ref)
  }
}

// ================= K4: resolve owner -> inst/cat, else stuff =================
__global__ void k_resolve(const int* __restrict__ wsI, int* __restrict__ out) {
  const int t = threadIdx.x;
  const int pid = blockIdx.x*256 + t;
  const int b = pid >> 18;
  __shared__ int s_val[ND];
  __shared__ int s_cnt[NC];
  if (t < ND) s_val[t] = wsI[OFF_VAL + b*ND + t];
  if (t >= 128 && t < 128 + NC) s_cnt[t - 128] = wsI[OFF_COUNTS + b*32 + (t - 128)];
  __syncthreads();
  const int o = out[pid];                // owner (sorted rank) or sentinel
  int inst, cat;
  if (o < ND) {
    int val = s_val[o];
    inst = val & 0xffff;
    cat  = val >> 16;
  } else {
    inst = -1;
    int cls = ((const unsigned char*)wsI)[OFF_SEGCLS*4 + pid];
    cat = (cls >= 2 && s_cnt[cls] > 4096) ? cls + 90 : 0;
  }
  out[pid] = inst;
  out[NB*OH*OW + pid] = cat;
}

extern "C" void kernel_launch(void* const* d_in, const int* in_sizes, int n_in,
                              void* d_out, int out_size, void* d_ws, size_t ws_size,
                              hipStream_t stream) {
  const float* boxes   = (const float*)d_in[0];
  const int*   classes = (const int*)d_in[1];
  const float* scores  = (const float*)d_in[2];
  const float* dmasks  = (const float*)d_in[3];
  const float* seg     = (const float*)d_in[4];
  int* wsI = (int*)d_ws;
  int* out = (int*)d_out;

  hipMemsetAsync(wsI + OFF_COUNTS, 0, NB*32*sizeof(int), stream);   // class counters
  k_segmask<<<NSEG + NB*ND, 256, 0, stream>>>(boxes, classes, scores, dmasks, seg, wsI, out);
  k_scan   <<<NB, 64, 0, stream>>>(wsI);
  k_paint  <<<NB*ND, 256, 0, stream>>>(wsI, out);
  k_resolve<<<(NB*OH*OW)/256, 256, 0, stream>>>(wsI, out);
}